// Round 17
// baseline (174.017 us; speedup 1.0000x reference)
//
#include <hip/hip_runtime.h>
#include <math.h>

// GraphAttentionBlock: B=1, N=4096, E=256, H=8, D=32, fp32 in/out.
// R30: staging-dedup notch 2. R29 (128q/8-wave, 170.1us) halved staging;
// now 256 q-rows / 16 waves / 1024 threads, grid (16,8,2) = 256 blocks:
// each (h,kt) tile staged by 16 blocks (~64MB L2->LDS) and each wave
// issues exactly ONE global_load_lds per PAIR (role: w>>3 = tile-of-pair,
// (w>>2)&1 = K/V, w&3 = quarter). vmcnt(0) at pair top waits on a single
// own op issued one full pair-compute earlier. Occupancy offered unchanged
// (1 block/CU x 16 waves = prev 2 x 8); LDS still 32KB; TILE body
// byte-identical to thrice-verified R28/R29. Buffer rotation invariant
// unchanged. 4 launches.

#define NTOK 4096
#define EDIM 256
#define HEADS 8
#define HD 32
#define NSPLIT 2
#define QSCALE 0.17677669529663687f            // 1/sqrt(32)
#define LOG2E 1.4426950408889634f
#define CINIT (-11.541560327111707f)           // -8 * log2(e)

typedef __attribute__((ext_vector_type(8))) short bf16x8;
typedef __attribute__((ext_vector_type(4))) float f32x4;
typedef __attribute__((ext_vector_type(4))) unsigned long long u64x4;

typedef __attribute__((address_space(3))) unsigned char lds_u8;
typedef const __attribute__((address_space(1))) unsigned char gl_u8;

static __device__ inline short f2bf(float f) {          // RNE
    unsigned u = __float_as_uint(f);
    u = (u + 0x7FFFu + ((u >> 16) & 1u)) >> 16;
    return (short)u;
}
// truncating bf16x2 pack: one v_perm_b32 (hi16 of a -> lo, hi16 of b -> hi)
static __device__ inline unsigned packtrunc(float a, float b) {
    return __builtin_amdgcn_perm(__float_as_uint(b), __float_as_uint(a),
                                 0x07060302u);
}
// p = (mask bit for this lane) ? v : 0   -- one VALU op, sgpr-pair mask
static __device__ inline float sel_mask(float v, unsigned long long m) {
    float r;
    asm("v_cndmask_b32 %0, 0, %1, %2" : "=v"(r) : "v"(v), "s"(m));
    return r;
}

// ---- prep: adjacency -> S^T bitmask + bf16 casts --------------------------
// maskT[qb*1024+kt*16+b*4+j] bit l = adj[qb*16+(l&15)][kt*64+b*16+((l>>4)&3)*4+j]
// mask work batched: 2048 blocks x 4 wave-units x 8 iterations (w stride 8192)
__global__ __launch_bounds__(256) void prep(
    const int* __restrict__ adj, unsigned long long* __restrict__ maskT,
    const float* __restrict__ x,  const float* __restrict__ Wq,
    const float* __restrict__ Wk, const float* __restrict__ Wv,
    const float* __restrict__ Wo,
    short* __restrict__ xb,  short* __restrict__ wqb,
    short* __restrict__ wkb, short* __restrict__ wvb,
    short* __restrict__ wob)
{
    const int bid = blockIdx.x;
    if (bid < 2048) {
        const int wb = bid * 4 + (threadIdx.x >> 6);
        const int l = threadIdx.x & 63;
        const int lrow = l & 15;
        const int lc4 = ((l >> 4) & 3) * 4;
#pragma unroll
        for (int i = 0; i < 8; ++i) {
            const int w = wb + i * 8192;             // (qb,kt,b)
            const int qb = w >> 8;
            const int kt = (w >> 2) & 63;
            const int b = w & 3;
            const int row = qb * 16 + lrow;
            const int col = kt * 64 + b * 16 + lc4;
            const int4 av = *(const int4*)&adj[row * NTOK + col];
            const unsigned long long m0 = __ballot(av.x != 0);
            const unsigned long long m1 = __ballot(av.y != 0);
            const unsigned long long m2 = __ballot(av.z != 0);
            const unsigned long long m3 = __ballot(av.w != 0);
            if (l == 0) {
                unsigned long long* dst = &maskT[(size_t)w * 4];
                dst[0] = m0; dst[1] = m1; dst[2] = m2; dst[3] = m3;
            }
        }
    } else {
        const int gid = (bid - 2048) * 256 + threadIdx.x;
        const int e = gid * 4;
        const float* src; short* dst; int off;
        if (e < NTOK * EDIM) { src = x; dst = xb; off = e; }
        else {
            const int r = e - NTOK * EDIM;
            const int wsel = r >> 16;
            off = r & 65535;
            src = (wsel == 0) ? Wq : (wsel == 1) ? Wk : (wsel == 2) ? Wv : Wo;
            dst = (wsel == 0) ? wqb : (wsel == 1) ? wkb : (wsel == 2) ? wvb : wob;
        }
        float4 v = *(const float4*)&src[off];
        uint2 t;
        t.x = (unsigned short)f2bf(v.x) | ((unsigned)(unsigned short)f2bf(v.y) << 16);
        t.y = (unsigned short)f2bf(v.z) | ((unsigned)(unsigned short)f2bf(v.w) << 16);
        *(uint2*)&dst[off] = t;
    }
}

// ---- QKV projection via MFMA, 16x64 per wave; q/k head-major -------------
// V output transposed AND PI-permuted per 32-token block (see R27 header).
__global__ __launch_bounds__(256) void qkv_mfma(
    const short* __restrict__ xb,
    const short* __restrict__ Wqb, const short* __restrict__ Wkb,
    const short* __restrict__ Wvb,
    const float* __restrict__ bq, const float* __restrict__ bk,
    const float* __restrict__ bv,
    short* __restrict__ qo, short* __restrict__ ko, short* __restrict__ vto)
{
    const int tid = threadIdx.x;
    const int wv = tid >> 6, lane = tid & 63;
    const int grp = lane >> 4, lcol = lane & 15;
    const int wsel = blockIdx.y >> 2;                  // 0=Q 1=K 2=V
    const int n0 = (blockIdx.y & 3) << 6;
    const int m0 = blockIdx.x * 64 + wv * 16;
    const short* __restrict__ W = (wsel == 0) ? Wqb : (wsel == 1) ? Wkb : Wvb;
    const float* __restrict__ bias = (wsel == 0) ? bq : (wsel == 1) ? bk : bv;

    bf16x8 af[8];
#pragma unroll
    for (int k = 0; k < 8; ++k)
        af[k] = *(const bf16x8*)&xb[(m0 + lcol) * 256 + k * 32 + grp * 8];

    f32x4 acc[4] = {};
#pragma unroll
    for (int k = 0; k < 8; ++k) {
#pragma unroll
        for (int t = 0; t < 4; ++t) {
            const bf16x8 bt =
                *(const bf16x8*)&W[(n0 + t * 16 + lcol) * 256 + k * 32 + grp * 8];
            acc[t] = __builtin_amdgcn_mfma_f32_16x16x32_bf16(af[k], bt, acc[t], 0, 0, 0);
        }
    }
#pragma unroll
    for (int t = 0; t < 4; ++t) {
        const int feat = n0 + t * 16 + lcol;
        const float bval = bias[feat];
        const int h = feat >> 5, d = feat & 31;
        if (wsel == 2) {
            uint2 o;
            o.x = (unsigned short)f2bf(acc[t][0] + bval) |
                  ((unsigned)(unsigned short)f2bf(acc[t][1] + bval) << 16);
            o.y = (unsigned short)f2bf(acc[t][2] + bval) |
                  ((unsigned)(unsigned short)f2bf(acc[t][3] + bval) << 16);
            // PI-permute the 4-token granule within its 64-token tile:
            // tt = wv*16+grp*4; np = (tt>>5)*32 + ((tt>>2)&3)*8 + ((tt>>4)&1)*4
            const int tb = blockIdx.x * 64;
            const int tt = (m0 - tb) + grp * 4;
            const int np = ((tt >> 5) << 5) + ((tt >> 2) & 3) * 8 +
                           (((tt >> 4) & 1) << 2);
            *(uint2*)&vto[h * (HD * NTOK) + d * NTOK + tb + np] = o;
        } else {
            short* __restrict__ out = (wsel == 0) ? qo : ko;
            // fold 1/sqrt(D) * log2(e) into Q so attn uses raw exp2
            const float sc = (wsel == 0) ? (QSCALE * LOG2E) : 1.0f;
#pragma unroll
            for (int j = 0; j < 4; ++j)
                out[h * (NTOK * HD) + (m0 + grp * 4 + j) * HD + d] =
                    f2bf((acc[t][j] + bval) * sc);
        }
    }
}

// ---- MFMA flash attention: 256q/16-wave blocks, pair-tile, in-reg P ------
__global__ __launch_bounds__(1024) void attn_mfma(
    const short* __restrict__ qg, const short* __restrict__ kg,
    const short* __restrict__ vtg, const unsigned long long* __restrict__ maskT,
    float* __restrict__ o_part, float* __restrict__ l_part)
{
    const int h = blockIdx.y;
    const int split = blockIdx.z;
    const int q0 = blockIdx.x << 8;               // 256 q-rows per block
    const short* __restrict__ Q  = qg  + h * (NTOK * HD);
    const short* __restrict__ K  = kg  + h * (NTOK * HD);
    const short* __restrict__ Vt = vtg + h * (HD * NTOK);

    __shared__ short Ks[4][64][32];      // 16KB, 64B rows, DMA-linear
    __shared__ short Vs[4][32][64];      // 16KB, octet-XOR swizzled

    const int tid = threadIdx.x;
    const int wv = tid >> 6;                      // 0..15
    const int lane = tid & 63;
    const int grp = lane >> 4;
    const int lcol = lane & 15;
    const int q0w = q0 + wv * 16;
    const int wvu = __builtin_amdgcn_readfirstlane(wv);
    // staging role: tpar = tile-of-pair, isK = K/V, sub = quarter
    const int tpar = wvu >> 3;
    const bool isK = ((wvu >> 2) & 1) == 0;
    const int sub = wvu & 3;

    // staging coords (1 DMA per wave per pair):
    //   K quarter sub: rows sub*16+(l>>2), oct l&3
    //   V quarter sub: rows sub*8+(l>>3), pre-swizzled oct (l&7)^(row&7)
    const int k_row = sub * 16 + (lane >> 2);
    const int k_oct = lane & 3;
    const int v_row = sub * 8 + (lane >> 3);
    const int v_oct = (lane & 7) ^ (v_row & 7);
    const short* __restrict__ kbase = &K[k_row * HD + k_oct * 8];
    const short* __restrict__ vbase = &Vt[v_row * NTOK + v_oct * 8];

    // Q as B-operand: B[n=lcol(qrow)][k=grp*8+j(d)]
    const bf16x8 qfrag = *(const bf16x8*)&Q[(q0w + lcol) * HD + grp * 8];

    const int qb = __builtin_amdgcn_readfirstlane(blockIdx.x * 16 + wv);
    const unsigned long long* __restrict__ mbase = maskT + (size_t)qb * 1024;

    f32x4 ot[2] = {};     // O^T C-layout: row=grp*4+j (d), col=lcol (qrow)
    f32x4 lacc = {};      // column sums of P via mfma(ones, pf, .)
    const f32x4 cinit = {CINIT, CINIT, CINIT, CINIT};
    bf16x8 ones;
#pragma unroll
    for (int i = 0; i < 8; ++i) ones[i] = (short)0x3F80;   // bf16 1.0

    const int tps = 64 / (int)gridDim.z;   // 32 tiles/split (kt_begin %4==0)
    const int kt_begin = split * tps;
    const int kt_end = kt_begin + tps;

// stage BOTH tiles of a pair; each wave issues its single assigned DMA.
// KTA/KTB are the pair's tiles; buffers derived as (KT)&3.
#define STAGEPAIR(KTA, KTB)                                                  \
    {                                                                        \
        const int ktm = tpar ? (KTB) : (KTA);                                \
        const int bufm = ktm & 3;                                            \
        const int k0s = ktm << 6;                                            \
        if (isK)                                                             \
            __builtin_amdgcn_global_load_lds(                                \
                (gl_u8*)(kbase + k0s * HD),                                  \
                (lds_u8*)((unsigned char*)&Ks[bufm][0][0] + (sub << 10)),    \
                16, 0, 0);                                                   \
        else                                                                 \
            __builtin_amdgcn_global_load_lds(                                \
                (gl_u8*)(vbase + k0s),                                       \
                (lds_u8*)((unsigned char*)&Vs[bufm][0][0] + (sub << 10)),    \
                16, 0, 0);                                                   \
    }

// one 64-key tile from buffer BUF, mask ptr MP: K/V b128 reads (PI storage
// keeps V conflict-free), S-MFMA, in-register softmax (tau binding), PV.
#define TILE(BUF, MP)                                                        \
    {                                                                        \
        const u64x4 wa = (MP)[0], wb = (MP)[1], wc = (MP)[2], wd = (MP)[3];  \
        bf16x8 kf[4], vf[4];                                                 \
        _Pragma("unroll")                                                    \
        for (int b = 0; b < 4; ++b)                                          \
            kf[b] = *(const bf16x8*)&Ks[BUF][b * 16 + lcol][grp * 8];        \
        _Pragma("unroll")                                                    \
        for (int c = 0; c < 2; ++c) {                                        \
            vf[c * 2 + 0] = *(const bf16x8*)                                 \
                &Vs[BUF][c * 16 + lcol][(grp ^ (lcol & 7)) * 8];             \
            vf[c * 2 + 1] = *(const bf16x8*)                                 \
                &Vs[BUF][c * 16 + lcol][((4 + grp) ^ (lcol & 7)) * 8];       \
        }                                                                    \
        f32x4 s[4];                                                          \
        __builtin_amdgcn_s_setprio(1);                                       \
        _Pragma("unroll")                                                    \
        for (int b = 0; b < 4; ++b)                                          \
            s[b] = __builtin_amdgcn_mfma_f32_16x16x32_bf16(                  \
                kf[b], qfrag, cinit, 0, 0, 0);                               \
        __builtin_amdgcn_s_setprio(0);                                       \
        uint2 pk[4];                                                         \
        _Pragma("unroll")                                                    \
        for (int b = 0; b < 4; ++b) {                                        \
            const u64x4 wj = (b == 0) ? wa : (b == 1) ? wb                   \
                             : (b == 2) ? wc : wd;                           \
            const float p0 = sel_mask(__builtin_amdgcn_exp2f(s[b][0]), wj[0]); \
            const float p1 = sel_mask(__builtin_amdgcn_exp2f(s[b][1]), wj[1]); \
            const float p2 = sel_mask(__builtin_amdgcn_exp2f(s[b][2]), wj[2]); \
            const float p3 = sel_mask(__builtin_amdgcn_exp2f(s[b][3]), wj[3]); \
            pk[b].x = packtrunc(p0, p1);                                     \
            pk[b].y = packtrunc(p2, p3);                                     \
        }                                                                    \
        struct U4 { uint2 a, b; };                                           \
        U4 u0 = {pk[0], pk[1]}, u1 = {pk[2], pk[3]};                         \
        const bf16x8 pf0 = __builtin_bit_cast(bf16x8, u0);                   \
        const bf16x8 pf1 = __builtin_bit_cast(bf16x8, u1);                   \
        __builtin_amdgcn_s_setprio(1);                                       \
        ot[0] = __builtin_amdgcn_mfma_f32_16x16x32_bf16(vf[0], pf0, ot[0], 0, 0, 0); \
        ot[0] = __builtin_amdgcn_mfma_f32_16x16x32_bf16(vf[1], pf1, ot[0], 0, 0, 0); \
        ot[1] = __builtin_amdgcn_mfma_f32_16x16x32_bf16(vf[2], pf0, ot[1], 0, 0, 0); \
        ot[1] = __builtin_amdgcn_mfma_f32_16x16x32_bf16(vf[3], pf1, ot[1], 0, 0, 0); \
        lacc  = __builtin_amdgcn_mfma_f32_16x16x32_bf16(ones, pf0, lacc, 0, 0, 0);   \
        lacc  = __builtin_amdgcn_mfma_f32_16x16x32_bf16(ones, pf1, lacc, 0, 0, 0);   \
        __builtin_amdgcn_s_setprio(0);                                       \
    }

    STAGEPAIR(kt_begin, kt_begin + 1)

    for (int kt = kt_begin; kt < kt_end; kt += 2) {
        // own single DMA was issued one full pair-compute ago -> cheap drain
        asm volatile("s_waitcnt vmcnt(0)" ::: "memory");
        __builtin_amdgcn_s_barrier();
        __builtin_amdgcn_sched_barrier(0);

        // both tiles' mask words (scalar, issued early)
        const u64x4* mpA = (const u64x4*)(mbase + kt * 16);
        const u64x4* mpB = (const u64x4*)(mbase + kt * 16 + 16);

        // stage the next pair into the previous pair's buffers (readers
        // finished last iteration; all waves passed this barrier)
        if (kt + 2 < kt_end) STAGEPAIR(kt + 2, kt + 3)

        // two independent chains: B's exp2/pack overlaps A's PV MFMAs
        TILE(kt & 3, mpA)
        TILE((kt + 1) & 3, mpB)
    }
#undef STAGEPAIR
#undef TILE

    float* __restrict__ ob = o_part + split * (NTOK * EDIM);
#pragma unroll
    for (int c = 0; c < 2; ++c) {
        float4 st;
        st.x = ot[c][0]; st.y = ot[c][1]; st.z = ot[c][2]; st.w = ot[c][3];
        *(float4*)&ob[(q0w + lcol) * EDIM + h * HD + c * 16 + grp * 4] = st;
    }
    // every lane holds l[qrow] in lacc[0] (A=ones -> all C-rows equal)
    if (grp == 0)
        l_part[split * (NTOK * HEADS) + (q0w + lcol) * HEADS + h] = lacc[0];
}

// ---- output projection, combine fused: Y = ((Σo)/(Σl)) @ Wo^T + bo -------
// grid (256): block = 16 rows x all 256 cols. Each of 4 waves takes a
// 64-col slice; af (same 16 rows) built redundantly per wave -- the 3
// repeat reads are L1/L2-hot, so unique o_part traffic is 8MB.
template <int NS>
__global__ __launch_bounds__(256) void out_mfma(
    const float* __restrict__ o_part, const float* __restrict__ l_part,
    const short* __restrict__ Wob, const float* __restrict__ bo,
    float* __restrict__ Y)
{
    const int tid = threadIdx.x;
    const int wv = tid >> 6, lane = tid & 63;
    const int grp = lane >> 4, lcol = lane & 15;
    const int m0 = blockIdx.x << 4;            // 16 rows per block
    const int n0 = wv << 6;                    // 64 cols per wave
    const int r = m0 + lcol;

    bf16x8 af[8];
#pragma unroll
    for (int k = 0; k < 8; ++k) {
        float4 s0 = {0.f, 0.f, 0.f, 0.f}, s1 = {0.f, 0.f, 0.f, 0.f};
        float lv = 0.f;
#pragma unroll
        for (int s = 0; s < NS; ++s) {
            const float* op = &o_part[s * (NTOK * EDIM) + r * EDIM + k * 32 + grp * 8];
            const float4 t0 = *(const float4*)op;
            const float4 t1 = *(const float4*)(op + 4);
            s0.x += t0.x; s0.y += t0.y; s0.z += t0.z; s0.w += t0.w;
            s1.x += t1.x; s1.y += t1.y; s1.z += t1.z; s1.w += t1.w;
            lv += l_part[s * (NTOK * HEADS) + r * HEADS + k];
        }
        const float inv = 1.0f / lv;
        bf16x8 t;
        t[0] = f2bf(s0.x * inv); t[1] = f2bf(s0.y * inv);
        t[2] = f2bf(s0.z * inv); t[3] = f2bf(s0.w * inv);
        t[4] = f2bf(s1.x * inv); t[5] = f2bf(s1.y * inv);
        t[6] = f2bf(s1.z * inv); t[7] = f2bf(s1.w * inv);
        af[k] = t;
    }

    f32x4 acc[4] = {};
#pragma unroll
    for (int k = 0; k < 8; ++k) {
#pragma unroll
        for (int t = 0; t < 4; ++t) {
            const bf16x8 bt =
                *(const bf16x8*)&Wob[(n0 + t * 16 + lcol) * 256 + k * 32 + grp * 8];
            acc[t] = __builtin_amdgcn_mfma_f32_16x16x32_bf16(af[k], bt, acc[t], 0, 0, 0);
        }
    }
#pragma unroll
    for (int t = 0; t < 4; ++t) {
        const float bval = bo[n0 + t * 16 + lcol];
#pragma unroll
        for (int j = 0; j < 4; ++j)
            Y[(m0 + grp * 4 + j) * EDIM + n0 + t * 16 + lcol] = acc[t][j] + bval;
    }
}

extern "C" void kernel_launch(void* const* d_in, const int* in_sizes, int n_in,
                              void* d_out, int out_size, void* d_ws, size_t ws_size,
                              hipStream_t stream) {
    (void)in_sizes; (void)n_in; (void)out_size; (void)ws_size;
    const float* x  = (const float*)d_in[0];
    const int*  adj = (const int*)d_in[1];
    const float* Wq = (const float*)d_in[2];
    const float* bq = (const float*)d_in[3];
    const float* Wk = (const float*)d_in[4];
    const float* bk = (const float*)d_in[5];
    const float* Wv = (const float*)d_in[6];
    const float* bv = (const float*)d_in[7];
    const float* Wo = (const float*)d_in[8];
    const float* bo = (const float*)d_in[9];

    char* ws = (char*)d_ws;
    short* x_bf  = (short*)(ws);                        // 2 MB  [N][256]
    short* q_ws  = (short*)(ws + (2u << 20));           // 2 MB  [H][N][32]
    short* k_ws  = (short*)(ws + (4u << 20));           // 2 MB
    short* vt_ws = (short*)(ws + (6u << 20));           // 2 MB  [H][32][N] PI-perm
    unsigned long long* maskT =
        (unsigned long long*)(ws + (8u << 20));         // 2 MB
    short* Wq_bf = (short*)(ws + (10u << 20));          // 128 KB each
    short* Wk_bf = Wq_bf + (EDIM * EDIM);
    short* Wv_bf = Wk_bf + (EDIM * EDIM);
    short* Wo_bf = Wv_bf + (EDIM * EDIM);
    float* l_part = (float*)(ws + (11u << 20));         // 256 KB [2][N][8]
    float* o_part = (float*)(ws + (12u << 20));         // 8 MB   [2][N][256]

    prep<<<dim3(2048 + 1280), 256, 0, stream>>>(
        adj, maskT, x, Wq, Wk, Wv, Wo, x_bf, Wq_bf, Wk_bf, Wv_bf, Wo_bf);
    qkv_mfma<<<dim3(64, 12), 256, 0, stream>>>(x_bf, Wq_bf, Wk_bf, Wv_bf,
                                               bq, bk, bv, q_ws, k_ws, vt_ws);
    attn_mfma<<<dim3(16, HEADS, NSPLIT), 1024, 0, stream>>>(
        q_ws, k_ws, vt_ws, maskT, o_part, l_part);
    out_mfma<NSPLIT><<<dim3(256), 256, 0, stream>>>(o_part, l_part, Wo_bf, bo,
                                                    (float*)d_out);
}

// Round 18
// 168.571 us; speedup vs baseline: 1.0323x; 1.0323x over previous
//
#include <hip/hip_runtime.h>
#include <math.h>

// GraphAttentionBlock: B=1, N=4096, E=256, H=8, D=32, fp32 in/out.
// R31: R29 revert (R30's 16-wave/1-block-per-CU blocks regressed 170.1->
// 174.0: barrier group of 16 with no co-resident block = straggler
// exposure; 8-wave/2-block-per-CU is the right granularity) + quad-tile:
// 4 tiles per barrier interval, 8 LDS buffers (64KB -> 2 blocks/CU =
// exactly what the 512-block grid offers; occupancy unchanged). Barriers
// halve again (8/split) and the scheduler gets 4 independent
// S->exp2->PV chains per region (pair gave +2us in R28). Staging roles
// unchanged from R29 (waves 0-3 K quarters, 4-7 V quarters, 1 DMA/wave/
// tile). Rotation: quad P+1 staged during quad P into quad P-1's buffers
// (readers passed this barrier). TILE body byte-identical to verified
// R28/R29. 4 launches.

#define NTOK 4096
#define EDIM 256
#define HEADS 8
#define HD 32
#define NSPLIT 2
#define QSCALE 0.17677669529663687f            // 1/sqrt(32)
#define LOG2E 1.4426950408889634f
#define CINIT (-11.541560327111707f)           // -8 * log2(e)

typedef __attribute__((ext_vector_type(8))) short bf16x8;
typedef __attribute__((ext_vector_type(4))) float f32x4;
typedef __attribute__((ext_vector_type(4))) unsigned long long u64x4;

typedef __attribute__((address_space(3))) unsigned char lds_u8;
typedef const __attribute__((address_space(1))) unsigned char gl_u8;

static __device__ inline short f2bf(float f) {          // RNE
    unsigned u = __float_as_uint(f);
    u = (u + 0x7FFFu + ((u >> 16) & 1u)) >> 16;
    return (short)u;
}
// truncating bf16x2 pack: one v_perm_b32 (hi16 of a -> lo, hi16 of b -> hi)
static __device__ inline unsigned packtrunc(float a, float b) {
    return __builtin_amdgcn_perm(__float_as_uint(b), __float_as_uint(a),
                                 0x07060302u);
}
// p = (mask bit for this lane) ? v : 0   -- one VALU op, sgpr-pair mask
static __device__ inline float sel_mask(float v, unsigned long long m) {
    float r;
    asm("v_cndmask_b32 %0, 0, %1, %2" : "=v"(r) : "v"(v), "s"(m));
    return r;
}

// ---- prep: adjacency -> S^T bitmask + bf16 casts --------------------------
// maskT[qb*1024+kt*16+b*4+j] bit l = adj[qb*16+(l&15)][kt*64+b*16+((l>>4)&3)*4+j]
// mask work batched: 2048 blocks x 4 wave-units x 8 iterations (w stride 8192)
__global__ __launch_bounds__(256) void prep(
    const int* __restrict__ adj, unsigned long long* __restrict__ maskT,
    const float* __restrict__ x,  const float* __restrict__ Wq,
    const float* __restrict__ Wk, const float* __restrict__ Wv,
    const float* __restrict__ Wo,
    short* __restrict__ xb,  short* __restrict__ wqb,
    short* __restrict__ wkb, short* __restrict__ wvb,
    short* __restrict__ wob)
{
    const int bid = blockIdx.x;
    if (bid < 2048) {
        const int wb = bid * 4 + (threadIdx.x >> 6);
        const int l = threadIdx.x & 63;
        const int lrow = l & 15;
        const int lc4 = ((l >> 4) & 3) * 4;
#pragma unroll
        for (int i = 0; i < 8; ++i) {
            const int w = wb + i * 8192;             // (qb,kt,b)
            const int qb = w >> 8;
            const int kt = (w >> 2) & 63;
            const int b = w & 3;
            const int row = qb * 16 + lrow;
            const int col = kt * 64 + b * 16 + lc4;
            const int4 av = *(const int4*)&adj[row * NTOK + col];
            const unsigned long long m0 = __ballot(av.x != 0);
            const unsigned long long m1 = __ballot(av.y != 0);
            const unsigned long long m2 = __ballot(av.z != 0);
            const unsigned long long m3 = __ballot(av.w != 0);
            if (l == 0) {
                unsigned long long* dst = &maskT[(size_t)w * 4];
                dst[0] = m0; dst[1] = m1; dst[2] = m2; dst[3] = m3;
            }
        }
    } else {
        const int gid = (bid - 2048) * 256 + threadIdx.x;
        const int e = gid * 4;
        const float* src; short* dst; int off;
        if (e < NTOK * EDIM) { src = x; dst = xb; off = e; }
        else {
            const int r = e - NTOK * EDIM;
            const int wsel = r >> 16;
            off = r & 65535;
            src = (wsel == 0) ? Wq : (wsel == 1) ? Wk : (wsel == 2) ? Wv : Wo;
            dst = (wsel == 0) ? wqb : (wsel == 1) ? wkb : (wsel == 2) ? wvb : wob;
        }
        float4 v = *(const float4*)&src[off];
        uint2 t;
        t.x = (unsigned short)f2bf(v.x) | ((unsigned)(unsigned short)f2bf(v.y) << 16);
        t.y = (unsigned short)f2bf(v.z) | ((unsigned)(unsigned short)f2bf(v.w) << 16);
        *(uint2*)&dst[off] = t;
    }
}

// ---- QKV projection via MFMA, 16x64 per wave; q/k head-major -------------
// V output transposed AND PI-permuted per 32-token block (see R27 header).
__global__ __launch_bounds__(256) void qkv_mfma(
    const short* __restrict__ xb,
    const short* __restrict__ Wqb, const short* __restrict__ Wkb,
    const short* __restrict__ Wvb,
    const float* __restrict__ bq, const float* __restrict__ bk,
    const float* __restrict__ bv,
    short* __restrict__ qo, short* __restrict__ ko, short* __restrict__ vto)
{
    const int tid = threadIdx.x;
    const int wv = tid >> 6, lane = tid & 63;
    const int grp = lane >> 4, lcol = lane & 15;
    const int wsel = blockIdx.y >> 2;                  // 0=Q 1=K 2=V
    const int n0 = (blockIdx.y & 3) << 6;
    const int m0 = blockIdx.x * 64 + wv * 16;
    const short* __restrict__ W = (wsel == 0) ? Wqb : (wsel == 1) ? Wkb : Wvb;
    const float* __restrict__ bias = (wsel == 0) ? bq : (wsel == 1) ? bk : bv;

    bf16x8 af[8];
#pragma unroll
    for (int k = 0; k < 8; ++k)
        af[k] = *(const bf16x8*)&xb[(m0 + lcol) * 256 + k * 32 + grp * 8];

    f32x4 acc[4] = {};
#pragma unroll
    for (int k = 0; k < 8; ++k) {
#pragma unroll
        for (int t = 0; t < 4; ++t) {
            const bf16x8 bt =
                *(const bf16x8*)&W[(n0 + t * 16 + lcol) * 256 + k * 32 + grp * 8];
            acc[t] = __builtin_amdgcn_mfma_f32_16x16x32_bf16(af[k], bt, acc[t], 0, 0, 0);
        }
    }
#pragma unroll
    for (int t = 0; t < 4; ++t) {
        const int feat = n0 + t * 16 + lcol;
        const float bval = bias[feat];
        const int h = feat >> 5, d = feat & 31;
        if (wsel == 2) {
            uint2 o;
            o.x = (unsigned short)f2bf(acc[t][0] + bval) |
                  ((unsigned)(unsigned short)f2bf(acc[t][1] + bval) << 16);
            o.y = (unsigned short)f2bf(acc[t][2] + bval) |
                  ((unsigned)(unsigned short)f2bf(acc[t][3] + bval) << 16);
            // PI-permute the 4-token granule within its 64-token tile:
            // tt = wv*16+grp*4; np = (tt>>5)*32 + ((tt>>2)&3)*8 + ((tt>>4)&1)*4
            const int tb = blockIdx.x * 64;
            const int tt = (m0 - tb) + grp * 4;
            const int np = ((tt >> 5) << 5) + ((tt >> 2) & 3) * 8 +
                           (((tt >> 4) & 1) << 2);
            *(uint2*)&vto[h * (HD * NTOK) + d * NTOK + tb + np] = o;
        } else {
            short* __restrict__ out = (wsel == 0) ? qo : ko;
            // fold 1/sqrt(D) * log2(e) into Q so attn uses raw exp2
            const float sc = (wsel == 0) ? (QSCALE * LOG2E) : 1.0f;
#pragma unroll
            for (int j = 0; j < 4; ++j)
                out[h * (NTOK * HD) + (m0 + grp * 4 + j) * HD + d] =
                    f2bf((acc[t][j] + bval) * sc);
        }
    }
}

// ---- MFMA flash attention: 128q/8-wave blocks, quad-tile, in-register P --
__global__ __launch_bounds__(512) void attn_mfma(
    const short* __restrict__ qg, const short* __restrict__ kg,
    const short* __restrict__ vtg, const unsigned long long* __restrict__ maskT,
    float* __restrict__ o_part, float* __restrict__ l_part)
{
    const int h = blockIdx.y;
    const int split = blockIdx.z;
    const int q0 = blockIdx.x << 7;               // 128 q-rows per block
    const short* __restrict__ Q  = qg  + h * (NTOK * HD);
    const short* __restrict__ K  = kg  + h * (NTOK * HD);
    const short* __restrict__ Vt = vtg + h * (HD * NTOK);

    __shared__ short Ks[8][64][32];      // 32KB, 64B rows, DMA-linear
    __shared__ short Vs[8][32][64];      // 32KB, octet-XOR swizzled

    const int tid = threadIdx.x;
    const int wv = tid >> 6;                      // 0..7
    const int lane = tid & 63;
    const int grp = lane >> 4;
    const int lcol = lane & 15;
    const int q0w = q0 + wv * 16;
    const int wvu = __builtin_amdgcn_readfirstlane(wv);
    const bool isK = (wvu < 4);                   // wave role: K or V stager
    const int sub = wvu & 3;

    // staging coords: K wave w stages rows w*16+(l>>2), oct l&3 (1KB);
    // V wave w stages rows w*8+(l>>3), pre-swizzled oct (l&7)^(row&7).
    const int k_row = sub * 16 + (lane >> 2);
    const int k_oct = lane & 3;
    const int v_row = sub * 8 + (lane >> 3);
    const int v_oct = (lane & 7) ^ (v_row & 7);
    const short* __restrict__ kbase = &K[k_row * HD + k_oct * 8];
    const short* __restrict__ vbase = &Vt[v_row * NTOK + v_oct * 8];

    // Q as B-operand: B[n=lcol(qrow)][k=grp*8+j(d)]
    const bf16x8 qfrag = *(const bf16x8*)&Q[(q0w + lcol) * HD + grp * 8];

    const int qb = __builtin_amdgcn_readfirstlane(blockIdx.x * 8 + wv);
    const unsigned long long* __restrict__ mbase = maskT + (size_t)qb * 1024;

    f32x4 ot[2] = {};     // O^T C-layout: row=grp*4+j (d), col=lcol (qrow)
    f32x4 lacc = {};      // column sums of P via mfma(ones, pf, .)
    const f32x4 cinit = {CINIT, CINIT, CINIT, CINIT};
    bf16x8 ones;
#pragma unroll
    for (int i = 0; i < 8; ++i) ones[i] = (short)0x3F80;   // bf16 1.0

    const int tps = 64 / (int)gridDim.z;   // 32 tiles/split (kt_begin %8==0)
    const int kt_begin = split * tps;
    const int kt_end = kt_begin + tps;

// async DMA one 64-key tile (4KB K + 4KB V) into buffer (KT)&7; waves 0-3
// stage K quarters, waves 4-7 stage V quarters -- 1 instr per wave.
#define STAGE(KT)                                                            \
    {                                                                        \
        const int bufm = (KT) & 7;                                           \
        const int k0s = (KT) << 6;                                           \
        if (isK)                                                             \
            __builtin_amdgcn_global_load_lds(                                \
                (gl_u8*)(kbase + k0s * HD),                                  \
                (lds_u8*)((unsigned char*)&Ks[bufm][0][0] + (sub << 10)),    \
                16, 0, 0);                                                   \
        else                                                                 \
            __builtin_amdgcn_global_load_lds(                                \
                (gl_u8*)(vbase + k0s),                                       \
                (lds_u8*)((unsigned char*)&Vs[bufm][0][0] + (sub << 10)),    \
                16, 0, 0);                                                   \
    }

// one 64-key tile from buffer BUF, mask ptr MP: K/V b128 reads (PI storage
// keeps V conflict-free), S-MFMA, in-register softmax (tau binding), PV.
#define TILE(BUF, MP)                                                        \
    {                                                                        \
        const u64x4 wa = (MP)[0], wb = (MP)[1], wc = (MP)[2], wd = (MP)[3];  \
        bf16x8 kf[4], vf[4];                                                 \
        _Pragma("unroll")                                                    \
        for (int b = 0; b < 4; ++b)                                          \
            kf[b] = *(const bf16x8*)&Ks[BUF][b * 16 + lcol][grp * 8];        \
        _Pragma("unroll")                                                    \
        for (int c = 0; c < 2; ++c) {                                        \
            vf[c * 2 + 0] = *(const bf16x8*)                                 \
                &Vs[BUF][c * 16 + lcol][(grp ^ (lcol & 7)) * 8];             \
            vf[c * 2 + 1] = *(const bf16x8*)                                 \
                &Vs[BUF][c * 16 + lcol][((4 + grp) ^ (lcol & 7)) * 8];       \
        }                                                                    \
        f32x4 s[4];                                                          \
        __builtin_amdgcn_s_setprio(1);                                       \
        _Pragma("unroll")                                                    \
        for (int b = 0; b < 4; ++b)                                          \
            s[b] = __builtin_amdgcn_mfma_f32_16x16x32_bf16(                  \
                kf[b], qfrag, cinit, 0, 0, 0);                               \
        __builtin_amdgcn_s_setprio(0);                                       \
        uint2 pk[4];                                                         \
        _Pragma("unroll")                                                    \
        for (int b = 0; b < 4; ++b) {                                        \
            const u64x4 wj = (b == 0) ? wa : (b == 1) ? wb                   \
                             : (b == 2) ? wc : wd;                           \
            const float p0 = sel_mask(__builtin_amdgcn_exp2f(s[b][0]), wj[0]); \
            const float p1 = sel_mask(__builtin_amdgcn_exp2f(s[b][1]), wj[1]); \
            const float p2 = sel_mask(__builtin_amdgcn_exp2f(s[b][2]), wj[2]); \
            const float p3 = sel_mask(__builtin_amdgcn_exp2f(s[b][3]), wj[3]); \
            pk[b].x = packtrunc(p0, p1);                                     \
            pk[b].y = packtrunc(p2, p3);                                     \
        }                                                                    \
        struct U4 { uint2 a, b; };                                           \
        U4 u0 = {pk[0], pk[1]}, u1 = {pk[2], pk[3]};                         \
        const bf16x8 pf0 = __builtin_bit_cast(bf16x8, u0);                   \
        const bf16x8 pf1 = __builtin_bit_cast(bf16x8, u1);                   \
        __builtin_amdgcn_s_setprio(1);                                       \
        ot[0] = __builtin_amdgcn_mfma_f32_16x16x32_bf16(vf[0], pf0, ot[0], 0, 0, 0); \
        ot[0] = __builtin_amdgcn_mfma_f32_16x16x32_bf16(vf[1], pf1, ot[0], 0, 0, 0); \
        ot[1] = __builtin_amdgcn_mfma_f32_16x16x32_bf16(vf[2], pf0, ot[1], 0, 0, 0); \
        ot[1] = __builtin_amdgcn_mfma_f32_16x16x32_bf16(vf[3], pf1, ot[1], 0, 0, 0); \
        lacc  = __builtin_amdgcn_mfma_f32_16x16x32_bf16(ones, pf0, lacc, 0, 0, 0);   \
        lacc  = __builtin_amdgcn_mfma_f32_16x16x32_bf16(ones, pf1, lacc, 0, 0, 0);   \
        __builtin_amdgcn_s_setprio(0);                                       \
    }

    STAGE(kt_begin)
    STAGE(kt_begin + 1)
    STAGE(kt_begin + 2)
    STAGE(kt_begin + 3)

    for (int kt = kt_begin; kt < kt_end; kt += 4) {
        // quad's DMA was issued one full quad-compute ago -> cheap drain
        asm volatile("s_waitcnt vmcnt(0)" ::: "memory");
        __builtin_amdgcn_s_barrier();
        __builtin_amdgcn_sched_barrier(0);

        // all four tiles' mask words (scalar, issued early)
        const u64x4* mpA = (const u64x4*)(mbase + kt * 16);
        const u64x4* mpB = (const u64x4*)(mbase + kt * 16 + 16);
        const u64x4* mpC = (const u64x4*)(mbase + kt * 16 + 32);
        const u64x4* mpD = (const u64x4*)(mbase + kt * 16 + 48);

        // stage the next quad into the previous quad's buffers (readers
        // finished last iteration; all waves passed this barrier)
        if (kt + 4 < kt_end) {
            STAGE(kt + 4)
            STAGE(kt + 5)
            STAGE(kt + 6)
            STAGE(kt + 7)
        }

        // four independent chains: later tiles' exp2/pack overlap earlier
        // tiles' PV MFMAs
        TILE(kt & 7, mpA)
        TILE((kt + 1) & 7, mpB)
        TILE((kt + 2) & 7, mpC)
        TILE((kt + 3) & 7, mpD)
    }
#undef STAGE
#undef TILE

    float* __restrict__ ob = o_part + split * (NTOK * EDIM);
#pragma unroll
    for (int c = 0; c < 2; ++c) {
        float4 st;
        st.x = ot[c][0]; st.y = ot[c][1]; st.z = ot[c][2]; st.w = ot[c][3];
        *(float4*)&ob[(q0w + lcol) * EDIM + h * HD + c * 16 + grp * 4] = st;
    }
    // every lane holds l[qrow] in lacc[0] (A=ones -> all C-rows equal)
    if (grp == 0)
        l_part[split * (NTOK * HEADS) + (q0w + lcol) * HEADS + h] = lacc[0];
}

// ---- output projection, combine fused: Y = ((Σo)/(Σl)) @ Wo^T + bo -------
// grid (256): block = 16 rows x all 256 cols. Each of 4 waves takes a
// 64-col slice; af (same 16 rows) built redundantly per wave -- the 3
// repeat reads are L1/L2-hot, so unique o_part traffic is 8MB.
template <int NS>
__global__ __launch_bounds__(256) void out_mfma(
    const float* __restrict__ o_part, const float* __restrict__ l_part,
    const short* __restrict__ Wob, const float* __restrict__ bo,
    float* __restrict__ Y)
{
    const int tid = threadIdx.x;
    const int wv = tid >> 6, lane = tid & 63;
    const int grp = lane >> 4, lcol = lane & 15;
    const int m0 = blockIdx.x << 4;            // 16 rows per block
    const int n0 = wv << 6;                    // 64 cols per wave
    const int r = m0 + lcol;

    bf16x8 af[8];
#pragma unroll
    for (int k = 0; k < 8; ++k) {
        float4 s0 = {0.f, 0.f, 0.f, 0.f}, s1 = {0.f, 0.f, 0.f, 0.f};
        float lv = 0.f;
#pragma unroll
        for (int s = 0; s < NS; ++s) {
            const float* op = &o_part[s * (NTOK * EDIM) + r * EDIM + k * 32 + grp * 8];
            const float4 t0 = *(const float4*)op;
            const float4 t1 = *(const float4*)(op + 4);
            s0.x += t0.x; s0.y += t0.y; s0.z += t0.z; s0.w += t0.w;
            s1.x += t1.x; s1.y += t1.y; s1.z += t1.z; s1.w += t1.w;
            lv += l_part[s * (NTOK * HEADS) + r * HEADS + k];
        }
        const float inv = 1.0f / lv;
        bf16x8 t;
        t[0] = f2bf(s0.x * inv); t[1] = f2bf(s0.y * inv);
        t[2] = f2bf(s0.z * inv); t[3] = f2bf(s0.w * inv);
        t[4] = f2bf(s1.x * inv); t[5] = f2bf(s1.y * inv);
        t[6] = f2bf(s1.z * inv); t[7] = f2bf(s1.w * inv);
        af[k] = t;
    }

    f32x4 acc[4] = {};
#pragma unroll
    for (int k = 0; k < 8; ++k) {
#pragma unroll
        for (int t = 0; t < 4; ++t) {
            const bf16x8 bt =
                *(const bf16x8*)&Wob[(n0 + t * 16 + lcol) * 256 + k * 32 + grp * 8];
            acc[t] = __builtin_amdgcn_mfma_f32_16x16x32_bf16(af[k], bt, acc[t], 0, 0, 0);
        }
    }
#pragma unroll
    for (int t = 0; t < 4; ++t) {
        const float bval = bo[n0 + t * 16 + lcol];
#pragma unroll
        for (int j = 0; j < 4; ++j)
            Y[(m0 + grp * 4 + j) * EDIM + n0 + t * 16 + lcol] = acc[t][j] + bval;
    }
}

extern "C" void kernel_launch(void* const* d_in, const int* in_sizes, int n_in,
                              void* d_out, int out_size, void* d_ws, size_t ws_size,
                              hipStream_t stream) {
    (void)in_sizes; (void)n_in; (void)out_size; (void)ws_size;
    const float* x  = (const float*)d_in[0];
    const int*  adj = (const int*)d_in[1];
    const float* Wq = (const float*)d_in[2];
    const float* bq = (const float*)d_in[3];
    const float* Wk = (const float*)d_in[4];
    const float* bk = (const float*)d_in[5];
    const float* Wv = (const float*)d_in[6];
    const float* bv = (const float*)d_in[7];
    const float* Wo = (const float*)d_in[8];
    const float* bo = (const float*)d_in[9];

    char* ws = (char*)d_ws;
    short* x_bf  = (short*)(ws);                        // 2 MB  [N][256]
    short* q_ws  = (short*)(ws + (2u << 20));           // 2 MB  [H][N][32]
    short* k_ws  = (short*)(ws + (4u << 20));           // 2 MB
    short* vt_ws = (short*)(ws + (6u << 20));           // 2 MB  [H][32][N] PI-perm
    unsigned long long* maskT =
        (unsigned long long*)(ws + (8u << 20));         // 2 MB
    short* Wq_bf = (short*)(ws + (10u << 20));          // 128 KB each
    short* Wk_bf = Wq_bf + (EDIM * EDIM);
    short* Wv_bf = Wk_bf + (EDIM * EDIM);
    short* Wo_bf = Wv_bf + (EDIM * EDIM);
    float* l_part = (float*)(ws + (11u << 20));         // 256 KB [2][N][8]
    float* o_part = (float*)(ws + (12u << 20));         // 8 MB   [2][N][256]

    prep<<<dim3(2048 + 1280), 256, 0, stream>>>(
        adj, maskT, x, Wq, Wk, Wv, Wo, x_bf, Wq_bf, Wk_bf, Wv_bf, Wo_bf);
    qkv_mfma<<<dim3(64, 12), 256, 0, stream>>>(x_bf, Wq_bf, Wk_bf, Wv_bf,
                                               bq, bk, bv, q_ws, k_ws, vt_ws);
    attn_mfma<<<dim3(32, HEADS, NSPLIT), 512, 0, stream>>>(
        q_ws, k_ws, vt_ws, maskT, o_part, l_part);
    out_mfma<NSPLIT><<<dim3(256), 256, 0, stream>>>(o_part, l_part, Wo_bf, bo,
                                                    (float*)d_out);
}

// Round 19
// 168.069 us; speedup vs baseline: 1.0354x; 1.0030x over previous
//
#include <hip/hip_runtime.h>
#include <math.h>

// GraphAttentionBlock: B=1, N=4096, E=256, H=8, D=32, fp32 in/out.
// R32: R31 (quad-tile ILP, 168.6us best) + qkv Q-path transposed like V.
// Q's old path: 16 scalar 2B stores per wave per t-loop (stride-64B,
// unmergeable). New: Q stored [h][d][N] (no PI needed) -> 4 packed uint2
// stores per t-loop, coalesced, like the V path. attn reads Q ONCE per
// kernel, so its qfrag becomes 8 strided bf16 loads (4x32B segments,
// L2-hot, amortized over 32 tiles ~ free). K keeps the scalar path (its
// S-MFMA A-operand needs [k][d]-contiguous DMA; transpose provably
// reintroduces the R26 conflict). attn TILE/staging/out/prep untouched
// from R31. 4 launches.

#define NTOK 4096
#define EDIM 256
#define HEADS 8
#define HD 32
#define NSPLIT 2
#define QSCALE 0.17677669529663687f            // 1/sqrt(32)
#define LOG2E 1.4426950408889634f
#define CINIT (-11.541560327111707f)           // -8 * log2(e)

typedef __attribute__((ext_vector_type(8))) short bf16x8;
typedef __attribute__((ext_vector_type(4))) float f32x4;
typedef __attribute__((ext_vector_type(4))) unsigned long long u64x4;

typedef __attribute__((address_space(3))) unsigned char lds_u8;
typedef const __attribute__((address_space(1))) unsigned char gl_u8;

static __device__ inline short f2bf(float f) {          // RNE
    unsigned u = __float_as_uint(f);
    u = (u + 0x7FFFu + ((u >> 16) & 1u)) >> 16;
    return (short)u;
}
// truncating bf16x2 pack: one v_perm_b32 (hi16 of a -> lo, hi16 of b -> hi)
static __device__ inline unsigned packtrunc(float a, float b) {
    return __builtin_amdgcn_perm(__float_as_uint(b), __float_as_uint(a),
                                 0x07060302u);
}
// p = (mask bit for this lane) ? v : 0   -- one VALU op, sgpr-pair mask
static __device__ inline float sel_mask(float v, unsigned long long m) {
    float r;
    asm("v_cndmask_b32 %0, 0, %1, %2" : "=v"(r) : "v"(v), "s"(m));
    return r;
}

// ---- prep: adjacency -> S^T bitmask + bf16 casts --------------------------
// maskT[qb*1024+kt*16+b*4+j] bit l = adj[qb*16+(l&15)][kt*64+b*16+((l>>4)&3)*4+j]
// mask work batched: 2048 blocks x 4 wave-units x 8 iterations (w stride 8192)
__global__ __launch_bounds__(256) void prep(
    const int* __restrict__ adj, unsigned long long* __restrict__ maskT,
    const float* __restrict__ x,  const float* __restrict__ Wq,
    const float* __restrict__ Wk, const float* __restrict__ Wv,
    const float* __restrict__ Wo,
    short* __restrict__ xb,  short* __restrict__ wqb,
    short* __restrict__ wkb, short* __restrict__ wvb,
    short* __restrict__ wob)
{
    const int bid = blockIdx.x;
    if (bid < 2048) {
        const int wb = bid * 4 + (threadIdx.x >> 6);
        const int l = threadIdx.x & 63;
        const int lrow = l & 15;
        const int lc4 = ((l >> 4) & 3) * 4;
#pragma unroll
        for (int i = 0; i < 8; ++i) {
            const int w = wb + i * 8192;             // (qb,kt,b)
            const int qb = w >> 8;
            const int kt = (w >> 2) & 63;
            const int b = w & 3;
            const int row = qb * 16 + lrow;
            const int col = kt * 64 + b * 16 + lc4;
            const int4 av = *(const int4*)&adj[row * NTOK + col];
            const unsigned long long m0 = __ballot(av.x != 0);
            const unsigned long long m1 = __ballot(av.y != 0);
            const unsigned long long m2 = __ballot(av.z != 0);
            const unsigned long long m3 = __ballot(av.w != 0);
            if (l == 0) {
                unsigned long long* dst = &maskT[(size_t)w * 4];
                dst[0] = m0; dst[1] = m1; dst[2] = m2; dst[3] = m3;
            }
        }
    } else {
        const int gid = (bid - 2048) * 256 + threadIdx.x;
        const int e = gid * 4;
        const float* src; short* dst; int off;
        if (e < NTOK * EDIM) { src = x; dst = xb; off = e; }
        else {
            const int r = e - NTOK * EDIM;
            const int wsel = r >> 16;
            off = r & 65535;
            src = (wsel == 0) ? Wq : (wsel == 1) ? Wk : (wsel == 2) ? Wv : Wo;
            dst = (wsel == 0) ? wqb : (wsel == 1) ? wkb : (wsel == 2) ? wvb : wob;
        }
        float4 v = *(const float4*)&src[off];
        uint2 t;
        t.x = (unsigned short)f2bf(v.x) | ((unsigned)(unsigned short)f2bf(v.y) << 16);
        t.y = (unsigned short)f2bf(v.z) | ((unsigned)(unsigned short)f2bf(v.w) << 16);
        *(uint2*)&dst[off] = t;
    }
}

// ---- QKV projection via MFMA, 16x64 per wave -----------------------------
// Q output transposed [h][d][N] (uint2 packed); V transposed AND
// PI-permuted per 32-token block (R27); K row-major [n][d] (scalar).
__global__ __launch_bounds__(256) void qkv_mfma(
    const short* __restrict__ xb,
    const short* __restrict__ Wqb, const short* __restrict__ Wkb,
    const short* __restrict__ Wvb,
    const float* __restrict__ bq, const float* __restrict__ bk,
    const float* __restrict__ bv,
    short* __restrict__ qo, short* __restrict__ ko, short* __restrict__ vto)
{
    const int tid = threadIdx.x;
    const int wv = tid >> 6, lane = tid & 63;
    const int grp = lane >> 4, lcol = lane & 15;
    const int wsel = blockIdx.y >> 2;                  // 0=Q 1=K 2=V
    const int n0 = (blockIdx.y & 3) << 6;
    const int m0 = blockIdx.x * 64 + wv * 16;
    const short* __restrict__ W = (wsel == 0) ? Wqb : (wsel == 1) ? Wkb : Wvb;
    const float* __restrict__ bias = (wsel == 0) ? bq : (wsel == 1) ? bk : bv;

    bf16x8 af[8];
#pragma unroll
    for (int k = 0; k < 8; ++k)
        af[k] = *(const bf16x8*)&xb[(m0 + lcol) * 256 + k * 32 + grp * 8];

    f32x4 acc[4] = {};
#pragma unroll
    for (int k = 0; k < 8; ++k) {
#pragma unroll
        for (int t = 0; t < 4; ++t) {
            const bf16x8 bt =
                *(const bf16x8*)&W[(n0 + t * 16 + lcol) * 256 + k * 32 + grp * 8];
            acc[t] = __builtin_amdgcn_mfma_f32_16x16x32_bf16(af[k], bt, acc[t], 0, 0, 0);
        }
    }
#pragma unroll
    for (int t = 0; t < 4; ++t) {
        const int feat = n0 + t * 16 + lcol;
        const float bval = bias[feat];
        const int h = feat >> 5, d = feat & 31;
        if (wsel == 2) {
            uint2 o;
            o.x = (unsigned short)f2bf(acc[t][0] + bval) |
                  ((unsigned)(unsigned short)f2bf(acc[t][1] + bval) << 16);
            o.y = (unsigned short)f2bf(acc[t][2] + bval) |
                  ((unsigned)(unsigned short)f2bf(acc[t][3] + bval) << 16);
            // PI-permute the 4-token granule within its 64-token tile:
            // tt = wv*16+grp*4; np = (tt>>5)*32 + ((tt>>2)&3)*8 + ((tt>>4)&1)*4
            const int tb = blockIdx.x * 64;
            const int tt = (m0 - tb) + grp * 4;
            const int np = ((tt >> 5) << 5) + ((tt >> 2) & 3) * 8 +
                           (((tt >> 4) & 1) << 2);
            *(uint2*)&vto[h * (HD * NTOK) + d * NTOK + tb + np] = o;
        } else if (wsel == 0) {
            // Q transposed [h][d][N], scale folded; packed uint2 store
            const float sc = QSCALE * LOG2E;
            uint2 o;
            o.x = (unsigned short)f2bf((acc[t][0] + bval) * sc) |
                  ((unsigned)(unsigned short)f2bf((acc[t][1] + bval) * sc) << 16);
            o.y = (unsigned short)f2bf((acc[t][2] + bval) * sc) |
                  ((unsigned)(unsigned short)f2bf((acc[t][3] + bval) * sc) << 16);
            *(uint2*)&qo[h * (HD * NTOK) + d * NTOK + m0 + grp * 4] = o;
        } else {
            // K row-major [n][d] (attn DMA needs [k][d]-contiguous source)
#pragma unroll
            for (int j = 0; j < 4; ++j)
                ko[h * (NTOK * HD) + (m0 + grp * 4 + j) * HD + d] =
                    f2bf(acc[t][j] + bval);
        }
    }
}

// ---- MFMA flash attention: 128q/8-wave blocks, quad-tile, in-register P --
__global__ __launch_bounds__(512) void attn_mfma(
    const short* __restrict__ qg, const short* __restrict__ kg,
    const short* __restrict__ vtg, const unsigned long long* __restrict__ maskT,
    float* __restrict__ o_part, float* __restrict__ l_part)
{
    const int h = blockIdx.y;
    const int split = blockIdx.z;
    const int q0 = blockIdx.x << 7;               // 128 q-rows per block
    const short* __restrict__ QT = qg  + h * (HD * NTOK);   // [d][N]
    const short* __restrict__ K  = kg  + h * (NTOK * HD);
    const short* __restrict__ Vt = vtg + h * (HD * NTOK);

    __shared__ short Ks[8][64][32];      // 32KB, 64B rows, DMA-linear
    __shared__ short Vs[8][32][64];      // 32KB, octet-XOR swizzled

    const int tid = threadIdx.x;
    const int wv = tid >> 6;                      // 0..7
    const int lane = tid & 63;
    const int grp = lane >> 4;
    const int lcol = lane & 15;
    const int q0w = q0 + wv * 16;
    const int wvu = __builtin_amdgcn_readfirstlane(wv);
    const bool isK = (wvu < 4);                   // wave role: K or V stager
    const int sub = wvu & 3;

    // staging coords: K wave w stages rows w*16+(l>>2), oct l&3 (1KB);
    // V wave w stages rows w*8+(l>>3), pre-swizzled oct (l&7)^(row&7).
    const int k_row = sub * 16 + (lane >> 2);
    const int k_oct = lane & 3;
    const int v_row = sub * 8 + (lane >> 3);
    const int v_oct = (lane & 7) ^ (v_row & 7);
    const short* __restrict__ kbase = &K[k_row * HD + k_oct * 8];
    const short* __restrict__ vbase = &Vt[v_row * NTOK + v_oct * 8];

    // Q as B-operand from Q^T: lane needs q=q0w+lcol, d=grp*8+j (8 strided
    // bf16 loads, once per kernel, L2-hot, amortized over 32 tiles)
    bf16x8 qfrag;
#pragma unroll
    for (int j = 0; j < 8; ++j)
        qfrag[j] = QT[(grp * 8 + j) * NTOK + q0w + lcol];

    const int qb = __builtin_amdgcn_readfirstlane(blockIdx.x * 8 + wv);
    const unsigned long long* __restrict__ mbase = maskT + (size_t)qb * 1024;

    f32x4 ot[2] = {};     // O^T C-layout: row=grp*4+j (d), col=lcol (qrow)
    f32x4 lacc = {};      // column sums of P via mfma(ones, pf, .)
    const f32x4 cinit = {CINIT, CINIT, CINIT, CINIT};
    bf16x8 ones;
#pragma unroll
    for (int i = 0; i < 8; ++i) ones[i] = (short)0x3F80;   // bf16 1.0

    const int tps = 64 / (int)gridDim.z;   // 32 tiles/split (kt_begin %8==0)
    const int kt_begin = split * tps;
    const int kt_end = kt_begin + tps;

// async DMA one 64-key tile (4KB K + 4KB V) into buffer (KT)&7; waves 0-3
// stage K quarters, waves 4-7 stage V quarters -- 1 instr per wave.
#define STAGE(KT)                                                            \
    {                                                                        \
        const int bufm = (KT) & 7;                                           \
        const int k0s = (KT) << 6;                                           \
        if (isK)                                                             \
            __builtin_amdgcn_global_load_lds(                                \
                (gl_u8*)(kbase + k0s * HD),                                  \
                (lds_u8*)((unsigned char*)&Ks[bufm][0][0] + (sub << 10)),    \
                16, 0, 0);                                                   \
        else                                                                 \
            __builtin_amdgcn_global_load_lds(                                \
                (gl_u8*)(vbase + k0s),                                       \
                (lds_u8*)((unsigned char*)&Vs[bufm][0][0] + (sub << 10)),    \
                16, 0, 0);                                                   \
    }

// one 64-key tile from buffer BUF, mask ptr MP: K/V b128 reads (PI storage
// keeps V conflict-free), S-MFMA, in-register softmax (tau binding), PV.
#define TILE(BUF, MP)                                                        \
    {                                                                        \
        const u64x4 wa = (MP)[0], wb = (MP)[1], wc = (MP)[2], wd = (MP)[3];  \
        bf16x8 kf[4], vf[4];                                                 \
        _Pragma("unroll")                                                    \
        for (int b = 0; b < 4; ++b)                                          \
            kf[b] = *(const bf16x8*)&Ks[BUF][b * 16 + lcol][grp * 8];        \
        _Pragma("unroll")                                                    \
        for (int c = 0; c < 2; ++c) {                                        \
            vf[c * 2 + 0] = *(const bf16x8*)                                 \
                &Vs[BUF][c * 16 + lcol][(grp ^ (lcol & 7)) * 8];             \
            vf[c * 2 + 1] = *(const bf16x8*)                                 \
                &Vs[BUF][c * 16 + lcol][((4 + grp) ^ (lcol & 7)) * 8];       \
        }                                                                    \
        f32x4 s[4];                                                          \
        __builtin_amdgcn_s_setprio(1);                                       \
        _Pragma("unroll")                                                    \
        for (int b = 0; b < 4; ++b)                                          \
            s[b] = __builtin_amdgcn_mfma_f32_16x16x32_bf16(                  \
                kf[b], qfrag, cinit, 0, 0, 0);                               \
        __builtin_amdgcn_s_setprio(0);                                       \
        uint2 pk[4];                                                         \
        _Pragma("unroll")                                                    \
        for (int b = 0; b < 4; ++b) {                                        \
            const u64x4 wj = (b == 0) ? wa : (b == 1) ? wb                   \
                             : (b == 2) ? wc : wd;                           \
            const float p0 = sel_mask(__builtin_amdgcn_exp2f(s[b][0]), wj[0]); \
            const float p1 = sel_mask(__builtin_amdgcn_exp2f(s[b][1]), wj[1]); \
            const float p2 = sel_mask(__builtin_amdgcn_exp2f(s[b][2]), wj[2]); \
            const float p3 = sel_mask(__builtin_amdgcn_exp2f(s[b][3]), wj[3]); \
            pk[b].x = packtrunc(p0, p1);                                     \
            pk[b].y = packtrunc(p2, p3);                                     \
        }                                                                    \
        struct U4 { uint2 a, b; };                                           \
        U4 u0 = {pk[0], pk[1]}, u1 = {pk[2], pk[3]};                         \
        const bf16x8 pf0 = __builtin_bit_cast(bf16x8, u0);                   \
        const bf16x8 pf1 = __builtin_bit_cast(bf16x8, u1);                   \
        __builtin_amdgcn_s_setprio(1);                                       \
        ot[0] = __builtin_amdgcn_mfma_f32_16x16x32_bf16(vf[0], pf0, ot[0], 0, 0, 0); \
        ot[0] = __builtin_amdgcn_mfma_f32_16x16x32_bf16(vf[1], pf1, ot[0], 0, 0, 0); \
        ot[1] = __builtin_amdgcn_mfma_f32_16x16x32_bf16(vf[2], pf0, ot[1], 0, 0, 0); \
        ot[1] = __builtin_amdgcn_mfma_f32_16x16x32_bf16(vf[3], pf1, ot[1], 0, 0, 0); \
        lacc  = __builtin_amdgcn_mfma_f32_16x16x32_bf16(ones, pf0, lacc, 0, 0, 0);   \
        lacc  = __builtin_amdgcn_mfma_f32_16x16x32_bf16(ones, pf1, lacc, 0, 0, 0);   \
        __builtin_amdgcn_s_setprio(0);                                       \
    }

    STAGE(kt_begin)
    STAGE(kt_begin + 1)
    STAGE(kt_begin + 2)
    STAGE(kt_begin + 3)

    for (int kt = kt_begin; kt < kt_end; kt += 4) {
        // quad's DMA was issued one full quad-compute ago -> cheap drain
        asm volatile("s_waitcnt vmcnt(0)" ::: "memory");
        __builtin_amdgcn_s_barrier();
        __builtin_amdgcn_sched_barrier(0);

        // all four tiles' mask words (scalar, issued early)
        const u64x4* mpA = (const u64x4*)(mbase + kt * 16);
        const u64x4* mpB = (const u64x4*)(mbase + kt * 16 + 16);
        const u64x4* mpC = (const u64x4*)(mbase + kt * 16 + 32);
        const u64x4* mpD = (const u64x4*)(mbase + kt * 16 + 48);

        // stage the next quad into the previous quad's buffers (readers
        // finished last iteration; all waves passed this barrier)
        if (kt + 4 < kt_end) {
            STAGE(kt + 4)
            STAGE(kt + 5)
            STAGE(kt + 6)
            STAGE(kt + 7)
        }

        // four independent chains: later tiles' exp2/pack overlap earlier
        // tiles' PV MFMAs
        TILE(kt & 7, mpA)
        TILE((kt + 1) & 7, mpB)
        TILE((kt + 2) & 7, mpC)
        TILE((kt + 3) & 7, mpD)
    }
#undef STAGE
#undef TILE

    float* __restrict__ ob = o_part + split * (NTOK * EDIM);
#pragma unroll
    for (int c = 0; c < 2; ++c) {
        float4 st;
        st.x = ot[c][0]; st.y = ot[c][1]; st.z = ot[c][2]; st.w = ot[c][3];
        *(float4*)&ob[(q0w + lcol) * EDIM + h * HD + c * 16 + grp * 4] = st;
    }
    // every lane holds l[qrow] in lacc[0] (A=ones -> all C-rows equal)
    if (grp == 0)
        l_part[split * (NTOK * HEADS) + (q0w + lcol) * HEADS + h] = lacc[0];
}

// ---- output projection, combine fused: Y = ((Σo)/(Σl)) @ Wo^T + bo -------
// grid (256): block = 16 rows x all 256 cols. Each of 4 waves takes a
// 64-col slice; af (same 16 rows) built redundantly per wave -- the 3
// repeat reads are L1/L2-hot, so unique o_part traffic is 8MB.
template <int NS>
__global__ __launch_bounds__(256) void out_mfma(
    const float* __restrict__ o_part, const float* __restrict__ l_part,
    const short* __restrict__ Wob, const float* __restrict__ bo,
    float* __restrict__ Y)
{
    const int tid = threadIdx.x;
    const int wv = tid >> 6, lane = tid & 63;
    const int grp = lane >> 4, lcol = lane & 15;
    const int m0 = blockIdx.x << 4;            // 16 rows per block
    const int n0 = wv << 6;                    // 64 cols per wave
    const int r = m0 + lcol;

    bf16x8 af[8];
#pragma unroll
    for (int k = 0; k < 8; ++k) {
        float4 s0 = {0.f, 0.f, 0.f, 0.f}, s1 = {0.f, 0.f, 0.f, 0.f};
        float lv = 0.f;
#pragma unroll
        for (int s = 0; s < NS; ++s) {
            const float* op = &o_part[s * (NTOK * EDIM) + r * EDIM + k * 32 + grp * 8];
            const float4 t0 = *(const float4*)op;
            const float4 t1 = *(const float4*)(op + 4);
            s0.x += t0.x; s0.y += t0.y; s0.z += t0.z; s0.w += t0.w;
            s1.x += t1.x; s1.y += t1.y; s1.z += t1.z; s1.w += t1.w;
            lv += l_part[s * (NTOK * HEADS) + r * HEADS + k];
        }
        const float inv = 1.0f / lv;
        bf16x8 t;
        t[0] = f2bf(s0.x * inv); t[1] = f2bf(s0.y * inv);
        t[2] = f2bf(s0.z * inv); t[3] = f2bf(s0.w * inv);
        t[4] = f2bf(s1.x * inv); t[5] = f2bf(s1.y * inv);
        t[6] = f2bf(s1.z * inv); t[7] = f2bf(s1.w * inv);
        af[k] = t;
    }

    f32x4 acc[4] = {};
#pragma unroll
    for (int k = 0; k < 8; ++k) {
#pragma unroll
        for (int t = 0; t < 4; ++t) {
            const bf16x8 bt =
                *(const bf16x8*)&Wob[(n0 + t * 16 + lcol) * 256 + k * 32 + grp * 8];
            acc[t] = __builtin_amdgcn_mfma_f32_16x16x32_bf16(af[k], bt, acc[t], 0, 0, 0);
        }
    }
#pragma unroll
    for (int t = 0; t < 4; ++t) {
        const float bval = bo[n0 + t * 16 + lcol];
#pragma unroll
        for (int j = 0; j < 4; ++j)
            Y[(m0 + grp * 4 + j) * EDIM + n0 + t * 16 + lcol] = acc[t][j] + bval;
    }
}

extern "C" void kernel_launch(void* const* d_in, const int* in_sizes, int n_in,
                              void* d_out, int out_size, void* d_ws, size_t ws_size,
                              hipStream_t stream) {
    (void)in_sizes; (void)n_in; (void)out_size; (void)ws_size;
    const float* x  = (const float*)d_in[0];
    const int*  adj = (const int*)d_in[1];
    const float* Wq = (const float*)d_in[2];
    const float* bq = (const float*)d_in[3];
    const float* Wk = (const float*)d_in[4];
    const float* bk = (const float*)d_in[5];
    const float* Wv = (const float*)d_in[6];
    const float* bv = (const float*)d_in[7];
    const float* Wo = (const float*)d_in[8];
    const float* bo = (const float*)d_in[9];

    char* ws = (char*)d_ws;
    short* x_bf  = (short*)(ws);                        // 2 MB  [N][256]
    short* q_ws  = (short*)(ws + (2u << 20));           // 2 MB  [H][32][N] Q^T
    short* k_ws  = (short*)(ws + (4u << 20));           // 2 MB  [H][N][32]
    short* vt_ws = (short*)(ws + (6u << 20));           // 2 MB  [H][32][N] PI-perm
    unsigned long long* maskT =
        (unsigned long long*)(ws + (8u << 20));         // 2 MB
    short* Wq_bf = (short*)(ws + (10u << 20));          // 128 KB each
    short* Wk_bf = Wq_bf + (EDIM * EDIM);
    short* Wv_bf = Wk_bf + (EDIM * EDIM);
    short* Wo_bf = Wv_bf + (EDIM * EDIM);
    float* l_part = (float*)(ws + (11u << 20));         // 256 KB [2][N][8]
    float* o_part = (float*)(ws + (12u << 20));         // 8 MB   [2][N][256]

    prep<<<dim3(2048 + 1280), 256, 0, stream>>>(
        adj, maskT, x, Wq, Wk, Wv, Wo, x_bf, Wq_bf, Wk_bf, Wv_bf, Wo_bf);
    qkv_mfma<<<dim3(64, 12), 256, 0, stream>>>(x_bf, Wq_bf, Wk_bf, Wv_bf,
                                               bq, bk, bv, q_ws, k_ws, vt_ws);
    attn_mfma<<<dim3(32, HEADS, NSPLIT), 512, 0, stream>>>(
        q_ws, k_ws, vt_ws, maskT, o_part, l_part);
    out_mfma<NSPLIT><<<dim3(256), 256, 0, stream>>>(o_part, l_part, Wo_bf, bo,
                                                    (float*)d_out);
}